// Round 8
// baseline (2632.504 us; speedup 1.0000x reference)
//
#include <hip/hip_runtime.h>
#include <math.h>

// ---------------------------------------------------------------------------
// B=64 graphs, NN=133 nodes. ONE persistent kernel (plain launch, 768 blocks
// x 256 thr) + software grid barrier (device-scope atomics). Co-residency is
// guaranteed by construction: __launch_bounds__(256,3) caps VGPR for >=3
// waves/EU -> 3 blocks/CU x 256 CUs = 768; LDS ~11KB/block (3x fits 160KB).
// Phases (grid-strided, R6-validated logic):
//  P0 prep (64 graph-blocks) || emb GEMM (399 tiles)      -> bC h0 ld152
//  P1 gemm1 t1=h0@gc1_w (532 tiles)                       -> bA ld256
//  P2 spmm1 y1=relu(A@t1+b1)                              -> bB
//  P3 pool1                                               -> bC
//  P4 gemm2 t2=p1@gc2_w (266)                             -> bA ld128
//  P5 spmm2                                               -> bB
//  P6 pool2                                               -> bC
//  P7 gemm3 t3=p2@gc3_w (266)                             -> bA ld76
//  P8 spmm3 y3                                            -> bB
//  P9 tail (64 blocks): pool3 fused + gc4 + fc1 + fin -> sigmoid -> out
// Sparse lists per row: front = a>1e-5 (spmm+pool), back = 0<a<=1e-5 (spmm).
// Barrier cnt/gen in d_ws, zeroed by captured hipMemsetAsync each call.
// ---------------------------------------------------------------------------

#define NN 133
#define NPAIR 64
#define G 768

struct GBar { int cnt; int gen; };

__device__ __forceinline__ void grid_bar(GBar* B)
{
    __syncthreads();
    if (threadIdx.x == 0) {
        __threadfence();
        int g = __hip_atomic_load(&B->gen, __ATOMIC_RELAXED,
                                  __HIP_MEMORY_SCOPE_AGENT);
        int a = __hip_atomic_fetch_add(&B->cnt, 1, __ATOMIC_ACQ_REL,
                                       __HIP_MEMORY_SCOPE_AGENT);
        if (a == G - 1) {
            __hip_atomic_store(&B->cnt, 0, __ATOMIC_RELAXED,
                               __HIP_MEMORY_SCOPE_AGENT);
            __hip_atomic_fetch_add(&B->gen, 1, __ATOMIC_RELEASE,
                                   __HIP_MEMORY_SCOPE_AGENT);
        } else {
            while (__hip_atomic_load(&B->gen, __ATOMIC_ACQUIRE,
                                     __HIP_MEMORY_SCOPE_AGENT) == g)
                __builtin_amdgcn_s_sleep(1);
        }
        __threadfence();
    }
    __syncthreads();
}

// ------------- GEMM core: one 64x64 tile, prefetch-pipelined ----------------
template<int VECA, int VECB, int RELU, int BIAS>
__device__ __forceinline__ void gemm_tile_core(
    const float* __restrict__ A, int lda, int K,
    const float* __restrict__ W, int N,
    const float* __restrict__ bias,
    float* __restrict__ C, int ldc, int padN,
    int m0, int n0, float (*As)[68], float (*Bs)[68], int tid)
{
    const int la_m = tid >> 2, la_k = (tid & 3) * 4;   // A: 64 rows x 4 float4
    const int lb_k = tid >> 4, lb_n = (tid & 15) * 4;  // B: 16 k-rows x 16 f4
    const int tx = tid & 15, ty = tid >> 4;
    const int r = m0 + la_m;

    float pa[4], pb[4];
    if (VECA) {
        float4 v = *reinterpret_cast<const float4*>(A + (size_t)r * lda + la_k);
        pa[0] = v.x; pa[1] = v.y; pa[2] = v.z; pa[3] = v.w;
    } else {
#pragma unroll
        for (int j = 0; j < 4; ++j) {
            int gk = la_k + j;
            pa[j] = (gk < K) ? A[(size_t)r * lda + gk] : 0.f;
        }
    }
    if (VECB) {
        if (lb_k < K) {
            float4 v = *reinterpret_cast<const float4*>(
                W + (size_t)lb_k * N + n0 + lb_n);
            pb[0] = v.x; pb[1] = v.y; pb[2] = v.z; pb[3] = v.w;
        } else { pb[0] = pb[1] = pb[2] = pb[3] = 0.f; }
    } else {
#pragma unroll
        for (int j = 0; j < 4; ++j) {
            int gn = n0 + lb_n + j;
            pb[j] = (lb_k < K && gn < N) ? W[(size_t)lb_k * N + gn] : 0.f;
        }
    }

    float acc[4][4] = {};
    for (int k0 = 0; k0 < K; k0 += 16) {
        __syncthreads();
#pragma unroll
        for (int j = 0; j < 4; ++j) As[la_k + j][la_m] = pa[j];
        *reinterpret_cast<float4*>(&Bs[lb_k][lb_n]) =
            make_float4(pb[0], pb[1], pb[2], pb[3]);
        __syncthreads();
        const int kn = k0 + 16;
        if (kn < K) {   // prefetch next k-tile (overlaps FMA block)
            if (VECA) {
                float4 v = *reinterpret_cast<const float4*>(
                    A + (size_t)r * lda + kn + la_k);
                pa[0] = v.x; pa[1] = v.y; pa[2] = v.z; pa[3] = v.w;
            } else {
#pragma unroll
                for (int j = 0; j < 4; ++j) {
                    int gk = kn + la_k + j;
                    pa[j] = (gk < K) ? A[(size_t)r * lda + gk] : 0.f;
                }
            }
            int gk = kn + lb_k;
            if (VECB) {
                if (gk < K) {
                    float4 v = *reinterpret_cast<const float4*>(
                        W + (size_t)gk * N + n0 + lb_n);
                    pb[0] = v.x; pb[1] = v.y; pb[2] = v.z; pb[3] = v.w;
                } else { pb[0] = pb[1] = pb[2] = pb[3] = 0.f; }
            } else {
#pragma unroll
                for (int j = 0; j < 4; ++j) {
                    int gn = n0 + lb_n + j;
                    pb[j] = (gk < K && gn < N) ? W[(size_t)gk * N + gn] : 0.f;
                }
            }
        }
#pragma unroll
        for (int k = 0; k < 16; ++k) {
            float4 av = *reinterpret_cast<const float4*>(&As[k][ty * 4]);
            float4 bv = *reinterpret_cast<const float4*>(&Bs[k][tx * 4]);
            float a[4] = {av.x, av.y, av.z, av.w};
            float b[4] = {bv.x, bv.y, bv.z, bv.w};
#pragma unroll
            for (int i = 0; i < 4; ++i)
#pragma unroll
                for (int j = 0; j < 4; ++j)
                    acc[i][j] = fmaf(a[i], b[j], acc[i][j]);
        }
    }
#pragma unroll
    for (int i = 0; i < 4; ++i) {
        int gm = m0 + ty * 4 + i;
#pragma unroll
        for (int j = 0; j < 4; ++j) {
            int gn = n0 + tx * 4 + j;
            if (gn < padN) {
                float v = 0.f;
                if (gn < N) {
                    v = acc[i][j];
                    if (BIAS) v += bias[gn];
                    if (RELU) v = fmaxf(v, 0.f);
                }
                C[(size_t)gm * ldc + gn] = v;
            }
        }
    }
}

// --------- prep: one block builds sparse pair lists for graph b -------------
__device__ __forceinline__ void prep_graph(
    const float* __restrict__ adj, int b,
    float2* __restrict__ pairs, int2* __restrict__ cnts,
    int* c0s, int* c1s, int tid)
{
    for (int i = tid; i < NN; i += 256) { c0s[i] = 0; c1s[i] = 0; }
    __syncthreads();
    const float* adjb = adj + (size_t)b * NN * NN;
    float2* pbg = pairs + (size_t)b * NN * NPAIR;
    for (int q = tid; q < NN * NN; q += 256) {
        int i = q / NN, j = q - i * NN;
        float a = adjb[q];
        if (a > 1e-5f) {
            int s = atomicAdd(&c0s[i], 1);
            pbg[i * NPAIR + s] = make_float2(a, __int_as_float(j));
        } else if (a > 0.f) {
            int s = atomicAdd(&c1s[i], 1);
            pbg[i * NPAIR + (NPAIR - 1) - s] = make_float2(a, __int_as_float(j));
        }
    }
    __syncthreads();
    for (int i = tid; i < NN; i += 256)
        cnts[b * NN + i] = make_int2(c0s[i], c1s[i]);
}

// --------- spmm phase: one wave per (row, 64-col chunk), grid-strided -------
__device__ __forceinline__ void spmm_phase(
    const float* __restrict__ t, int ld, int N,
    const float* __restrict__ bias,
    const float2* __restrict__ pairs, const int2* __restrict__ cnts,
    float* __restrict__ y, int chsh, int nblkitems)
{
    const int wave = threadIdx.x >> 6, lane = threadIdx.x & 63;
    for (int bi = blockIdx.x; bi < nblkitems; bi += G) {
        const int item = bi * 4 + wave;
        const int r = item >> chsh, ch = item & ((1 << chsh) - 1);
        const int b = r / NN;
        const int col0 = (ch << 6) + lane;
        const int col = min(col0, N - 1);       // clamp for safe loads
        const float2* pb = pairs + (size_t)r * NPAIR;
        const int2 c = cnts[r];
        const float* tb = t + (size_t)b * NN * ld;
        float s0 = 0.f, s1 = 0.f, s2 = 0.f, s3 = 0.f;
        int q = 0;
        for (; q + 4 <= c.x; q += 4) {          // 4 gathers in flight
            float2 f0 = pb[q], f1 = pb[q + 1], f2 = pb[q + 2], f3 = pb[q + 3];
            s0 = fmaf(f0.x, tb[(size_t)__float_as_int(f0.y) * ld + col], s0);
            s1 = fmaf(f1.x, tb[(size_t)__float_as_int(f1.y) * ld + col], s1);
            s2 = fmaf(f2.x, tb[(size_t)__float_as_int(f2.y) * ld + col], s2);
            s3 = fmaf(f3.x, tb[(size_t)__float_as_int(f3.y) * ld + col], s3);
        }
        for (; q < c.x; ++q) {
            float2 f = pb[q];
            s0 = fmaf(f.x, tb[(size_t)__float_as_int(f.y) * ld + col], s0);
        }
        for (int u = 0; u < c.y; ++u) {         // tiny-weight tail (spmm only)
            float2 f = pb[(NPAIR - 1) - u];
            s0 = fmaf(f.x, tb[(size_t)__float_as_int(f.y) * ld + col], s0);
        }
        if (col0 < N) {
            float s = (s0 + s1) + (s2 + s3) + bias[col0];
            y[(size_t)r * ld + col0] = fmaxf(s, 0.f);
        }
    }
}

// --------- pool phase: p[r,col] = max over front nbrs of y[j,col] -----------
__device__ __forceinline__ void pool_phase(
    const float* __restrict__ y, int ld, int N,
    const float2* __restrict__ pairs, const int2* __restrict__ cnts,
    float* __restrict__ p, int chsh, int nblkitems)
{
    const int wave = threadIdx.x >> 6, lane = threadIdx.x & 63;
    for (int bi = blockIdx.x; bi < nblkitems; bi += G) {
        const int item = bi * 4 + wave;
        const int r = item >> chsh, ch = item & ((1 << chsh) - 1);
        const int b = r / NN;
        const int col0 = (ch << 6) + lane;
        const int col = min(col0, N - 1);
        const float2* pb = pairs + (size_t)r * NPAIR;
        const int cx = cnts[r].x;
        const float* yb = y + (size_t)b * NN * ld;
        float m0 = 0.f, m1 = 0.f, m2 = 0.f, m3 = 0.f;
        int q = 0;
        for (; q + 4 <= cx; q += 4) {
            float2 f0 = pb[q], f1 = pb[q + 1], f2 = pb[q + 2], f3 = pb[q + 3];
            m0 = fmaxf(m0, yb[(size_t)__float_as_int(f0.y) * ld + col]);
            m1 = fmaxf(m1, yb[(size_t)__float_as_int(f1.y) * ld + col]);
            m2 = fmaxf(m2, yb[(size_t)__float_as_int(f2.y) * ld + col]);
            m3 = fmaxf(m3, yb[(size_t)__float_as_int(f3.y) * ld + col]);
        }
        for (; q < cx; ++q)
            m0 = fmaxf(m0, yb[(size_t)__float_as_int(pb[q].y) * ld + col]);
        if (col0 < N)
            p[(size_t)r * ld + col0] = fmaxf(fmaxf(m0, m1), fmaxf(m2, m3));
    }
}

// ------------------------------ the kernel ----------------------------------
__global__ __launch_bounds__(256, 3)
void gcn_all(const float* __restrict__ x, const float* __restrict__ adj,
             const float* __restrict__ emb_w, const float* __restrict__ emb_b,
             const float* __restrict__ gc1_w, const float* __restrict__ gc1_b,
             const float* __restrict__ gc2_w, const float* __restrict__ gc2_b,
             const float* __restrict__ gc3_w, const float* __restrict__ gc3_b,
             const float* __restrict__ gc4_w, const float* __restrict__ gc4_b,
             const float* __restrict__ fc1_w, const float* __restrict__ fc1_b,
             const float* __restrict__ fin_w, const float* __restrict__ fin_b,
             float2* __restrict__ pairs, int2* __restrict__ cnts,
             float* __restrict__ bA, float* __restrict__ bB,
             float* __restrict__ bC, GBar* bar, float* __restrict__ out)
{
    __shared__ float As[16][68];
    __shared__ float Bs[16][68];
    __shared__ int c0s[NN], c1s[NN];
    __shared__ float t4S[NN], y4S[NN], rS[3];
    const int tid = threadIdx.x;

    // P0: emb GEMM (items 0..398, padN=152 zero-fills cols 150/151 for VECA)
    //     + sparse prep (items 399..462)
    for (int it = blockIdx.x; it < 463; it += G) {
        if (it < 399)
            gemm_tile_core<0, 0, 1, 1>(x, 75, 75, emb_w, 150, emb_b,
                                       bC, 152, 152, (it / 3) * 64,
                                       (it % 3) * 64, As, Bs, tid);
        else
            prep_graph(adj, it - 399, pairs, cnts, c0s, c1s, tid);
    }
    grid_bar(bar);
    // P1: t1 = h0 @ gc1_w -> bA ld 256
    for (int it = blockIdx.x; it < 532; it += G)
        gemm_tile_core<1, 1, 0, 0>(bC, 152, 150, gc1_w, 256, nullptr,
                                   bA, 256, 256, (it / 4) * 64,
                                   (it % 4) * 64, As, Bs, tid);
    grid_bar(bar);
    // P2: y1 -> bB
    spmm_phase(bA, 256, 256, gc1_b, pairs, cnts, bB, 2, 8512);
    grid_bar(bar);
    // P3: p1 -> bC
    pool_phase(bB, 256, 256, pairs, cnts, bC, 2, 8512);
    grid_bar(bar);
    // P4: t2 = p1 @ gc2_w -> bA ld 128
    for (int it = blockIdx.x; it < 266; it += G)
        gemm_tile_core<1, 1, 0, 0>(bC, 256, 256, gc2_w, 128, nullptr,
                                   bA, 128, 128, (it / 2) * 64,
                                   (it % 2) * 64, As, Bs, tid);
    grid_bar(bar);
    // P5: y2 -> bB
    spmm_phase(bA, 128, 128, gc2_b, pairs, cnts, bB, 1, 4256);
    grid_bar(bar);
    // P6: p2 -> bC
    pool_phase(bB, 128, 128, pairs, cnts, bC, 1, 4256);
    grid_bar(bar);
    // P7: t3 = p2 @ gc3_w -> bA ld 76 (padN=76 zero-fills col 75)
    for (int it = blockIdx.x; it < 266; it += G)
        gemm_tile_core<1, 0, 0, 0>(bC, 128, 128, gc3_w, 75, nullptr,
                                   bA, 76, 76, (it / 2) * 64,
                                   (it % 2) * 64, As, Bs, tid);
    grid_bar(bar);
    // P8: y3 -> bB
    spmm_phase(bA, 76, 75, gc3_b, pairs, cnts, bB, 1, 4256);
    grid_bar(bar);

    // P9: tail, one block per graph (fused pool3 + gc4 + fc1 + fin)
    if (blockIdx.x < 64) {
        const int b = blockIdx.x;
        const int wave = tid >> 6, lane = tid & 63;
        const float* yb = bB + (size_t)b * NN * 76;
        const float gw0 = gc4_w[lane];
        const float gw1 = (lane < 11) ? gc4_w[64 + lane] : 0.f;
        const int c2 = 64 + min(lane, 10);
        for (int i = wave; i < NN; i += 4) {
            const float2* pb = pairs + ((size_t)b * NN + i) * NPAIR;
            const int cx = cnts[b * NN + i].x;
            float m0 = 0.f, m1 = 0.f;
            for (int q = 0; q < cx; ++q) {
                const float* row = yb + (size_t)__float_as_int(pb[q].y) * 76;
                m0 = fmaxf(m0, row[lane]);
                m1 = fmaxf(m1, row[c2]);
            }
            float v = m0 * gw0 + m1 * gw1;
#pragma unroll
            for (int off = 32; off; off >>= 1) v += __shfl_xor(v, off, 64);
            if (lane == 0) t4S[i] = v;
        }
        __syncthreads();
        if (tid < NN) {
            const float2* pb = pairs + ((size_t)b * NN + tid) * NPAIR;
            int2 c = cnts[b * NN + tid];
            float s = gc4_b[0];
            for (int q = 0; q < c.x; ++q) {
                float2 f = pb[q];
                s = fmaf(f.x, t4S[__float_as_int(f.y)], s);
            }
            for (int q = 0; q < c.y; ++q) {
                float2 f = pb[(NPAIR - 1) - q];
                s = fmaf(f.x, t4S[__float_as_int(f.y)], s);
            }
            y4S[tid] = fmaxf(s, 0.f);
        }
        __syncthreads();
        if (tid < 3) {
            float s = fc1_b[tid];
            for (int j = 0; j < 132; ++j)
                s = fmaf(y4S[1 + j], fc1_w[j * 3 + tid], s);
            rS[tid] = s;
        }
        __syncthreads();
        if (tid == 0) {
            float z = fin_b[0] + y4S[0] * fin_w[0] + rS[0] * fin_w[1]
                    + rS[1] * fin_w[2] + rS[2] * fin_w[3];
            out[b] = 1.f / (1.f + expf(-z));
        }
    }
}

extern "C" void kernel_launch(void* const* d_in, const int* in_sizes, int n_in,
                              void* d_out, int out_size, void* d_ws, size_t ws_size,
                              hipStream_t stream)
{
    const float* x     = (const float*)d_in[0];
    const float* adj   = (const float*)d_in[1];
    const float* emb_w = (const float*)d_in[2];
    const float* emb_b = (const float*)d_in[3];
    const float* gc1_w = (const float*)d_in[4];
    const float* gc1_b = (const float*)d_in[5];
    const float* gc2_w = (const float*)d_in[6];
    const float* gc2_b = (const float*)d_in[7];
    const float* gc3_w = (const float*)d_in[8];
    const float* gc3_b = (const float*)d_in[9];
    const float* gc4_w = (const float*)d_in[10];
    const float* gc4_b = (const float*)d_in[11];
    const float* fc1_w = (const float*)d_in[12];
    const float* fc1_b = (const float*)d_in[13];
    const float* fin_w = (const float*)d_in[14];
    const float* fin_b = (const float*)d_in[15];
    float* out = (float*)d_out;

    // ws: pairs 4.36MB | cnts 68KB | bA 8.72MB | bB 8.72MB | bC 8.72MB | bar
    const long MR = 64L * NN;                    // 8512
    float2* pairs = (float2*)d_ws;
    int2*   cnts  = (int2*)(pairs + MR * NPAIR);
    float*  bA    = (float*)(cnts + MR);
    float*  bB    = bA + MR * 256;
    float*  bC    = bB + MR * 256;
    GBar*   bar   = (GBar*)(bC + MR * 256);

    hipMemsetAsync(bar, 0, 64, stream);          // zero barrier state (captured)
    gcn_all<<<G, 256, 0, stream>>>(
        x, adj, emb_w, emb_b, gc1_w, gc1_b, gc2_w, gc2_b, gc3_w, gc3_b,
        gc4_w, gc4_b, fc1_w, fc1_b, fin_w, fin_b,
        pairs, cnts, bA, bB, bC, bar, out);
}

// Round 9
// 291.536 us; speedup vs baseline: 9.0298x; 9.0298x over previous
//
#include <hip/hip_runtime.h>
#include <math.h>

// ---------------------------------------------------------------------------
// B=64 graphs, NN=133 nodes. 10 plain launches (R6 structure, refined):
//  K1 prep_emb : blocks<399 -> emb GEMM tiles; blocks>=399 -> sparse prep
//  K2 gemm1 t1=h0@gc1_w (532 tiles)       K3 spmm1 (GRP=4, 1 wave/row)
//  K4 pool1 (GRP=4)                       K5 gemm2 (266)
//  K6 spmm2 (GRP=2)                       K7 pool2 (GRP=2)
//  K8 gemm3 (266)                         K9 spmm3 (GRP=2, N=75 masked)
//  K10 tail (64 blocks): pool3 fused + gc4 + fc1 + fin -> sigmoid
// Sparse lists per row: front = a>1e-5 (spmm+pool), back = 0<a<=1e-5 (spmm
// only). spmm/pool: one wave per adjacency row covering GRP*64 cols; pairs
// read as float4 (2 pairs) -> 2*GRP independent gathers in flight per step.
// 8512 waves per launch = 2128 blocks ~ one occupancy round.
// ---------------------------------------------------------------------------

#define NN 133
#define NPAIR 64

// ---------------- GEMM core: one 64x64 tile, prefetch-pipelined -------------
template<int VECA, int VECB, int RELU, int BIAS>
__device__ __forceinline__ void gemm_tile_core(
    const float* __restrict__ A, int lda, int K,
    const float* __restrict__ W, int N,
    const float* __restrict__ bias,
    float* __restrict__ C, int ldc, int padN,
    int m0, int n0, float (*As)[68], float (*Bs)[68], int tid)
{
    const int la_m = tid >> 2, la_k = (tid & 3) * 4;   // A: 64 rows x 4 float4
    const int lb_k = tid >> 4, lb_n = (tid & 15) * 4;  // B: 16 k-rows x 16 f4
    const int tx = tid & 15, ty = tid >> 4;
    const int r = m0 + la_m;

    float pa[4], pb[4];
    if (VECA) {
        float4 v = *reinterpret_cast<const float4*>(A + (size_t)r * lda + la_k);
        pa[0] = v.x; pa[1] = v.y; pa[2] = v.z; pa[3] = v.w;
    } else {
#pragma unroll
        for (int j = 0; j < 4; ++j) {
            int gk = la_k + j;
            pa[j] = (gk < K) ? A[(size_t)r * lda + gk] : 0.f;
        }
    }
    if (VECB) {
        if (lb_k < K) {
            float4 v = *reinterpret_cast<const float4*>(
                W + (size_t)lb_k * N + n0 + lb_n);
            pb[0] = v.x; pb[1] = v.y; pb[2] = v.z; pb[3] = v.w;
        } else { pb[0] = pb[1] = pb[2] = pb[3] = 0.f; }
    } else {
#pragma unroll
        for (int j = 0; j < 4; ++j) {
            int gn = n0 + lb_n + j;
            pb[j] = (lb_k < K && gn < N) ? W[(size_t)lb_k * N + gn] : 0.f;
        }
    }

    float acc[4][4] = {};
    for (int k0 = 0; k0 < K; k0 += 16) {
        __syncthreads();
#pragma unroll
        for (int j = 0; j < 4; ++j) As[la_k + j][la_m] = pa[j];
        *reinterpret_cast<float4*>(&Bs[lb_k][lb_n]) =
            make_float4(pb[0], pb[1], pb[2], pb[3]);
        __syncthreads();
        const int kn = k0 + 16;
        if (kn < K) {   // prefetch next k-tile (overlaps FMA block)
            if (VECA) {
                float4 v = *reinterpret_cast<const float4*>(
                    A + (size_t)r * lda + kn + la_k);
                pa[0] = v.x; pa[1] = v.y; pa[2] = v.z; pa[3] = v.w;
            } else {
#pragma unroll
                for (int j = 0; j < 4; ++j) {
                    int gk = kn + la_k + j;
                    pa[j] = (gk < K) ? A[(size_t)r * lda + gk] : 0.f;
                }
            }
            int gk = kn + lb_k;
            if (VECB) {
                if (gk < K) {
                    float4 v = *reinterpret_cast<const float4*>(
                        W + (size_t)gk * N + n0 + lb_n);
                    pb[0] = v.x; pb[1] = v.y; pb[2] = v.z; pb[3] = v.w;
                } else { pb[0] = pb[1] = pb[2] = pb[3] = 0.f; }
            } else {
#pragma unroll
                for (int j = 0; j < 4; ++j) {
                    int gn = n0 + lb_n + j;
                    pb[j] = (gk < K && gn < N) ? W[(size_t)gk * N + gn] : 0.f;
                }
            }
        }
#pragma unroll
        for (int k = 0; k < 16; ++k) {
            float4 av = *reinterpret_cast<const float4*>(&As[k][ty * 4]);
            float4 bv = *reinterpret_cast<const float4*>(&Bs[k][tx * 4]);
            float a[4] = {av.x, av.y, av.z, av.w};
            float b[4] = {bv.x, bv.y, bv.z, bv.w};
#pragma unroll
            for (int i = 0; i < 4; ++i)
#pragma unroll
                for (int j = 0; j < 4; ++j)
                    acc[i][j] = fmaf(a[i], b[j], acc[i][j]);
        }
    }
#pragma unroll
    for (int i = 0; i < 4; ++i) {
        int gm = m0 + ty * 4 + i;
#pragma unroll
        for (int j = 0; j < 4; ++j) {
            int gn = n0 + tx * 4 + j;
            if (gn < padN) {
                float v = 0.f;
                if (gn < N) {
                    v = acc[i][j];
                    if (BIAS) v += bias[gn];
                    if (RELU) v = fmaxf(v, 0.f);
                }
                C[(size_t)gm * ldc + gn] = v;
            }
        }
    }
}

template<int VECA, int VECB>
__global__ __launch_bounds__(256)
void gemm_k(const float* __restrict__ A, int lda, int K,
            const float* __restrict__ W, int N,
            float* __restrict__ C, int ldc, int padN, int tiles_n)
{
    __shared__ float As[16][68];
    __shared__ float Bs[16][68];
    const int t = blockIdx.x;
    gemm_tile_core<VECA, VECB, 0, 0>(
        A, lda, K, W, N, nullptr, C, ldc, padN,
        (t / tiles_n) * 64, (t % tiles_n) * 64, As, Bs, threadIdx.x);
}

// -------- K1: emb GEMM tiles (blocks<399) + sparse prep (blocks>=399) -------
__global__ __launch_bounds__(256)
void prep_emb_k(const float* __restrict__ x,
                const float* __restrict__ emb_w, const float* __restrict__ emb_b,
                const float* __restrict__ adj,
                float2* __restrict__ pairs, int2* __restrict__ cnts,
                float* __restrict__ h0)
{
    __shared__ float As[16][68];
    __shared__ float Bs[16][68];
    __shared__ int c0s[NN], c1s[NN];
    const int tid = threadIdx.x;
    if (blockIdx.x < 399) {
        const int t = blockIdx.x;
        gemm_tile_core<0, 0, 1, 1>(
            x, 75, 75, emb_w, 150, emb_b, h0, 152, 152,
            (t / 3) * 64, (t % 3) * 64, As, Bs, tid);
    } else {
        const int b = blockIdx.x - 399;
        for (int i = tid; i < NN; i += 256) { c0s[i] = 0; c1s[i] = 0; }
        __syncthreads();
        const float* adjb = adj + (size_t)b * NN * NN;
        float2* pbg = pairs + (size_t)b * NN * NPAIR;
        for (int q = tid; q < NN * NN; q += 256) {
            int i = q / NN, j = q - i * NN;
            float a = adjb[q];
            if (a > 1e-5f) {
                int s = atomicAdd(&c0s[i], 1);
                pbg[i * NPAIR + s] = make_float2(a, __int_as_float(j));
            } else if (a > 0.f) {
                int s = atomicAdd(&c1s[i], 1);
                pbg[i * NPAIR + (NPAIR - 1) - s] = make_float2(a, __int_as_float(j));
            }
        }
        __syncthreads();
        for (int i = tid; i < NN; i += 256)
            cnts[b * NN + i] = make_int2(c0s[i], c1s[i]);
    }
}

// -------- spmm: one wave per row, GRP*64 cols; 2*GRP gathers in flight ------
template<int GRP>
__global__ __launch_bounds__(256)
void spmm_k(const float* __restrict__ t, int ld, int N,
            const float* __restrict__ bias,
            const float2* __restrict__ pairs, const int2* __restrict__ cnts,
            float* __restrict__ y)
{
    const int wave = threadIdx.x >> 6, lane = threadIdx.x & 63;
    const int r = blockIdx.x * 4 + wave;        // 0..8511
    const int b = r / NN;
    int  c[GRP], sc[GRP];
#pragma unroll
    for (int u = 0; u < GRP; ++u) {
        c[u] = u * 64 + lane;
        sc[u] = min(c[u], N - 1);               // clamp for safe loads
    }
    const float2* pb = pairs + (size_t)r * NPAIR;
    const float4* pq = reinterpret_cast<const float4*>(pb);
    const int2 cc = cnts[r];
    const float* tb = t + (size_t)b * NN * ld;

    float a0[GRP], a1[GRP];
#pragma unroll
    for (int u = 0; u < GRP; ++u) { a0[u] = 0.f; a1[u] = 0.f; }
    int q = 0;
    for (; q + 2 <= cc.x; q += 2) {             // 2 pairs -> 2*GRP loads in flight
        float4 p2 = pq[q >> 1];
        const float* r0 = tb + (size_t)__float_as_int(p2.y) * ld;
        const float* r1 = tb + (size_t)__float_as_int(p2.w) * ld;
#pragma unroll
        for (int u = 0; u < GRP; ++u) {
            a0[u] = fmaf(p2.x, r0[sc[u]], a0[u]);
            a1[u] = fmaf(p2.z, r1[sc[u]], a1[u]);
        }
    }
    if (q < cc.x) {
        float2 f = pb[q];
        const float* r0 = tb + (size_t)__float_as_int(f.y) * ld;
#pragma unroll
        for (int u = 0; u < GRP; ++u) a0[u] = fmaf(f.x, r0[sc[u]], a0[u]);
    }
    for (int v = 0; v < cc.y; ++v) {            // tiny-weight tail (spmm only)
        float2 f = pb[(NPAIR - 1) - v];
        const float* r0 = tb + (size_t)__float_as_int(f.y) * ld;
#pragma unroll
        for (int u = 0; u < GRP; ++u) a0[u] = fmaf(f.x, r0[sc[u]], a0[u]);
    }
#pragma unroll
    for (int u = 0; u < GRP; ++u)
        if (c[u] < N)
            y[(size_t)r * ld + c[u]] = fmaxf(a0[u] + a1[u] + bias[c[u]], 0.f);
}

// -------- pool: p[r,col] = max over front nbrs j of y[j,col] (y>=0) ---------
template<int GRP>
__global__ __launch_bounds__(256)
void pool_k(const float* __restrict__ y, int ld, int N,
            const float2* __restrict__ pairs, const int2* __restrict__ cnts,
            float* __restrict__ p)
{
    const int wave = threadIdx.x >> 6, lane = threadIdx.x & 63;
    const int r = blockIdx.x * 4 + wave;
    const int b = r / NN;
    int  c[GRP], sc[GRP];
#pragma unroll
    for (int u = 0; u < GRP; ++u) {
        c[u] = u * 64 + lane;
        sc[u] = min(c[u], N - 1);
    }
    const float2* pb = pairs + (size_t)r * NPAIR;
    const float4* pq = reinterpret_cast<const float4*>(pb);
    const int cx = cnts[r].x;
    const float* yb = y + (size_t)b * NN * ld;

    float m0[GRP], m1[GRP];
#pragma unroll
    for (int u = 0; u < GRP; ++u) { m0[u] = 0.f; m1[u] = 0.f; }
    int q = 0;
    for (; q + 2 <= cx; q += 2) {
        float4 p2 = pq[q >> 1];
        const float* r0 = yb + (size_t)__float_as_int(p2.y) * ld;
        const float* r1 = yb + (size_t)__float_as_int(p2.w) * ld;
#pragma unroll
        for (int u = 0; u < GRP; ++u) {
            m0[u] = fmaxf(m0[u], r0[sc[u]]);
            m1[u] = fmaxf(m1[u], r1[sc[u]]);
        }
    }
    if (q < cx) {
        const float* r0 = yb + (size_t)__float_as_int(pb[q].y) * ld;
#pragma unroll
        for (int u = 0; u < GRP; ++u) m0[u] = fmaxf(m0[u], r0[sc[u]]);
    }
#pragma unroll
    for (int u = 0; u < GRP; ++u)
        if (c[u] < N)
            p[(size_t)r * ld + c[u]] = fmaxf(m0[u], m1[u]);
}

// -------- tail: fused pool3 -> gc4 -> sparse A -> fc1 -> fin -> sigmoid -----
__global__ __launch_bounds__(512)
void tail_k(const float* __restrict__ y3,   // ld 76, 75 valid cols
            const float2* __restrict__ pairs, const int2* __restrict__ cnts,
            const float* __restrict__ gc4_w, const float* __restrict__ gc4_b,
            const float* __restrict__ fc1_w, const float* __restrict__ fc1_b,
            const float* __restrict__ fin_w, const float* __restrict__ fin_b,
            float* __restrict__ out)
{
    const int b = blockIdx.x, tid = threadIdx.x;
    const int wave = tid >> 6, lane = tid & 63;
    __shared__ float t4S[NN], y4S[NN], rS[3];
    const float* yb = y3 + (size_t)b * NN * 76;

    const float gw0 = gc4_w[lane];                        // lane<=63<75 valid
    const float gw1 = (lane < 11) ? gc4_w[64 + lane] : 0.f;
    const int c2 = 64 + min(lane, 10);                    // safe 2nd col
    for (int i = wave; i < NN; i += 8) {
        const float2* pb = pairs + ((size_t)b * NN + i) * NPAIR;
        const int cx = cnts[b * NN + i].x;
        float m0 = 0.f, m1 = 0.f;
        for (int q = 0; q < cx; ++q) {
            const float* row = yb + (size_t)__float_as_int(pb[q].y) * 76;
            m0 = fmaxf(m0, row[lane]);
            m1 = fmaxf(m1, row[c2]);
        }
        float v = m0 * gw0 + m1 * gw1;
#pragma unroll
        for (int off = 32; off; off >>= 1) v += __shfl_xor(v, off, 64);
        if (lane == 0) t4S[i] = v;
    }
    __syncthreads();
    if (tid < NN) {
        const float2* pb = pairs + ((size_t)b * NN + tid) * NPAIR;
        int2 c = cnts[b * NN + tid];
        float s = gc4_b[0];
        for (int q = 0; q < c.x; ++q) {
            float2 f = pb[q];
            s = fmaf(f.x, t4S[__float_as_int(f.y)], s);
        }
        for (int q = 0; q < c.y; ++q) {
            float2 f = pb[(NPAIR - 1) - q];
            s = fmaf(f.x, t4S[__float_as_int(f.y)], s);
        }
        y4S[tid] = fmaxf(s, 0.f);
    }
    __syncthreads();
    if (tid < 3) {
        float s = fc1_b[tid];
        for (int j = 0; j < 132; ++j)
            s = fmaf(y4S[1 + j], fc1_w[j * 3 + tid], s);
        rS[tid] = s;
    }
    __syncthreads();
    if (tid == 0) {
        float z = fin_b[0] + y4S[0] * fin_w[0] + rS[0] * fin_w[1]
                + rS[1] * fin_w[2] + rS[2] * fin_w[3];
        out[b] = 1.f / (1.f + expf(-z));
    }
}

extern "C" void kernel_launch(void* const* d_in, const int* in_sizes, int n_in,
                              void* d_out, int out_size, void* d_ws, size_t ws_size,
                              hipStream_t stream)
{
    const float* x     = (const float*)d_in[0];
    const float* adj   = (const float*)d_in[1];
    const float* emb_w = (const float*)d_in[2];
    const float* emb_b = (const float*)d_in[3];
    const float* gc1_w = (const float*)d_in[4];
    const float* gc1_b = (const float*)d_in[5];
    const float* gc2_w = (const float*)d_in[6];
    const float* gc2_b = (const float*)d_in[7];
    const float* gc3_w = (const float*)d_in[8];
    const float* gc3_b = (const float*)d_in[9];
    const float* gc4_w = (const float*)d_in[10];
    const float* gc4_b = (const float*)d_in[11];
    const float* fc1_w = (const float*)d_in[12];
    const float* fc1_b = (const float*)d_in[13];
    const float* fin_w = (const float*)d_in[14];
    const float* fin_b = (const float*)d_in[15];
    float* out = (float*)d_out;

    // ws: pairs 4.36MB | cnts 68KB | bA 8.72MB | bB 8.72MB | bC 8.72MB
    const long MR = 64L * NN;                    // 8512
    float2* pairs = (float2*)d_ws;
    int2*   cnts  = (int2*)(pairs + MR * NPAIR);
    float*  bA    = (float*)(cnts + MR);
    float*  bB    = bA + MR * 256;
    float*  bC    = bB + MR * 256;

    // K1: emb GEMM (399 tiles) -> bC (h0, ld 152) + sparse prep (64 graphs)
    prep_emb_k<<<463, 256, 0, stream>>>(x, emb_w, emb_b, adj, pairs, cnts, bC);
    // K2: t1 = h0 @ gc1_w -> bA ld 256
    gemm_k<1, 1><<<532, 256, 0, stream>>>(bC, 152, 150, gc1_w, 256,
                                          bA, 256, 256, 4);
    // K3: y1 -> bB (one wave per row, 256 cols)
    spmm_k<4><<<2128, 256, 0, stream>>>(bA, 256, 256, gc1_b, pairs, cnts, bB);
    // K4: p1 -> bC
    pool_k<4><<<2128, 256, 0, stream>>>(bB, 256, 256, pairs, cnts, bC);
    // K5: t2 = p1 @ gc2_w -> bA ld 128
    gemm_k<1, 1><<<266, 256, 0, stream>>>(bC, 256, 256, gc2_w, 128,
                                          bA, 128, 128, 2);
    // K6: y2 -> bB
    spmm_k<2><<<2128, 256, 0, stream>>>(bA, 128, 128, gc2_b, pairs, cnts, bB);
    // K7: p2 -> bC
    pool_k<2><<<2128, 256, 0, stream>>>(bB, 128, 128, pairs, cnts, bC);
    // K8: t3 = p2 @ gc3_w -> bA ld 76 (padN=76 zero-fills col 75)
    gemm_k<1, 0><<<266, 256, 0, stream>>>(bC, 128, 128, gc3_w, 75,
                                          bA, 76, 76, 2);
    // K9: y3 -> bB (N=75, second col group masked)
    spmm_k<2><<<2128, 256, 0, stream>>>(bA, 76, 75, gc3_b, pairs, cnts, bB);
    // K10: tail (+fused pool3)
    tail_k<<<64, 512, 0, stream>>>(bB, pairs, cnts, gc4_w, gc4_b,
                                   fc1_w, fc1_b, fin_w, fin_b, out);
}

// Round 10
// 241.699 us; speedup vs baseline: 10.8916x; 1.2062x over previous
//
#include <hip/hip_runtime.h>
#include <math.h>

// ---------------------------------------------------------------------------
// B=64 graphs, NN=133 nodes. 11 plain launches:
//  K1 prep_emb : blocks<399 -> emb GEMM tiles; blocks>=399 -> sparse prep
//  K2 gemm1 t1=h0@gc1_w (532 tiles)       K3 spmm1 (GRP=4, 1 wave/row)
//  K4 pool1 (GRP=4)                       K5 gemm2 (266)
//  K6 spmm2 (GRP=2)                       K7 pool2 (GRP=2)
//  K8 gemm3 (266)                         K9 spmm3 (GRP=2, N=75 masked)
//  K10 t4_k: t4[r]=pool3(y3)[r].gc4_w, one wave/row (replaces pool3+old tail
//      gather — R9's 68us 64-block tail was the bottleneck)
//  K11 tail: y4 sparse from t4 + fc1 + fin -> sigmoid (64 blocks, trivial)
// Sparse lists per row: front = a>1e-5 (spmm+pool), back = 0<a<=1e-5 (spmm
// only). spmm/pool/t4: one wave per adjacency row; pairs read as float4
// (2 pairs) -> 2x independent gather chains in flight.
// ---------------------------------------------------------------------------

#define NN 133
#define NPAIR 64

// ---------------- GEMM core: one 64x64 tile, prefetch-pipelined -------------
template<int VECA, int VECB, int RELU, int BIAS>
__device__ __forceinline__ void gemm_tile_core(
    const float* __restrict__ A, int lda, int K,
    const float* __restrict__ W, int N,
    const float* __restrict__ bias,
    float* __restrict__ C, int ldc, int padN,
    int m0, int n0, float (*As)[68], float (*Bs)[68], int tid)
{
    const int la_m = tid >> 2, la_k = (tid & 3) * 4;   // A: 64 rows x 4 float4
    const int lb_k = tid >> 4, lb_n = (tid & 15) * 4;  // B: 16 k-rows x 16 f4
    const int tx = tid & 15, ty = tid >> 4;
    const int r = m0 + la_m;

    float pa[4], pb[4];
    if (VECA) {
        float4 v = *reinterpret_cast<const float4*>(A + (size_t)r * lda + la_k);
        pa[0] = v.x; pa[1] = v.y; pa[2] = v.z; pa[3] = v.w;
    } else {
#pragma unroll
        for (int j = 0; j < 4; ++j) {
            int gk = la_k + j;
            pa[j] = (gk < K) ? A[(size_t)r * lda + gk] : 0.f;
        }
    }
    if (VECB) {
        if (lb_k < K) {
            float4 v = *reinterpret_cast<const float4*>(
                W + (size_t)lb_k * N + n0 + lb_n);
            pb[0] = v.x; pb[1] = v.y; pb[2] = v.z; pb[3] = v.w;
        } else { pb[0] = pb[1] = pb[2] = pb[3] = 0.f; }
    } else {
#pragma unroll
        for (int j = 0; j < 4; ++j) {
            int gn = n0 + lb_n + j;
            pb[j] = (lb_k < K && gn < N) ? W[(size_t)lb_k * N + gn] : 0.f;
        }
    }

    float acc[4][4] = {};
    for (int k0 = 0; k0 < K; k0 += 16) {
        __syncthreads();
#pragma unroll
        for (int j = 0; j < 4; ++j) As[la_k + j][la_m] = pa[j];
        *reinterpret_cast<float4*>(&Bs[lb_k][lb_n]) =
            make_float4(pb[0], pb[1], pb[2], pb[3]);
        __syncthreads();
        const int kn = k0 + 16;
        if (kn < K) {   // prefetch next k-tile (overlaps FMA block)
            if (VECA) {
                float4 v = *reinterpret_cast<const float4*>(
                    A + (size_t)r * lda + kn + la_k);
                pa[0] = v.x; pa[1] = v.y; pa[2] = v.z; pa[3] = v.w;
            } else {
#pragma unroll
                for (int j = 0; j < 4; ++j) {
                    int gk = kn + la_k + j;
                    pa[j] = (gk < K) ? A[(size_t)r * lda + gk] : 0.f;
                }
            }
            int gk = kn + lb_k;
            if (VECB) {
                if (gk < K) {
                    float4 v = *reinterpret_cast<const float4*>(
                        W + (size_t)gk * N + n0 + lb_n);
                    pb[0] = v.x; pb[1] = v.y; pb[2] = v.z; pb[3] = v.w;
                } else { pb[0] = pb[1] = pb[2] = pb[3] = 0.f; }
            } else {
#pragma unroll
                for (int j = 0; j < 4; ++j) {
                    int gn = n0 + lb_n + j;
                    pb[j] = (gk < K && gn < N) ? W[(size_t)gk * N + gn] : 0.f;
                }
            }
        }
#pragma unroll
        for (int k = 0; k < 16; ++k) {
            float4 av = *reinterpret_cast<const float4*>(&As[k][ty * 4]);
            float4 bv = *reinterpret_cast<const float4*>(&Bs[k][tx * 4]);
            float a[4] = {av.x, av.y, av.z, av.w};
            float b[4] = {bv.x, bv.y, bv.z, bv.w};
#pragma unroll
            for (int i = 0; i < 4; ++i)
#pragma unroll
                for (int j = 0; j < 4; ++j)
                    acc[i][j] = fmaf(a[i], b[j], acc[i][j]);
        }
    }
#pragma unroll
    for (int i = 0; i < 4; ++i) {
        int gm = m0 + ty * 4 + i;
#pragma unroll
        for (int j = 0; j < 4; ++j) {
            int gn = n0 + tx * 4 + j;
            if (gn < padN) {
                float v = 0.f;
                if (gn < N) {
                    v = acc[i][j];
                    if (BIAS) v += bias[gn];
                    if (RELU) v = fmaxf(v, 0.f);
                }
                C[(size_t)gm * ldc + gn] = v;
            }
        }
    }
}

template<int VECA, int VECB>
__global__ __launch_bounds__(256)
void gemm_k(const float* __restrict__ A, int lda, int K,
            const float* __restrict__ W, int N,
            float* __restrict__ C, int ldc, int padN, int tiles_n)
{
    __shared__ float As[16][68];
    __shared__ float Bs[16][68];
    const int t = blockIdx.x;
    gemm_tile_core<VECA, VECB, 0, 0>(
        A, lda, K, W, N, nullptr, C, ldc, padN,
        (t / tiles_n) * 64, (t % tiles_n) * 64, As, Bs, threadIdx.x);
}

// -------- K1: emb GEMM tiles (blocks<399) + sparse prep (blocks>=399) -------
__global__ __launch_bounds__(256)
void prep_emb_k(const float* __restrict__ x,
                const float* __restrict__ emb_w, const float* __restrict__ emb_b,
                const float* __restrict__ adj,
                float2* __restrict__ pairs, int2* __restrict__ cnts,
                float* __restrict__ h0)
{
    __shared__ float As[16][68];
    __shared__ float Bs[16][68];
    __shared__ int c0s[NN], c1s[NN];
    const int tid = threadIdx.x;
    if (blockIdx.x < 399) {
        const int t = blockIdx.x;
        gemm_tile_core<0, 0, 1, 1>(
            x, 75, 75, emb_w, 150, emb_b, h0, 152, 152,
            (t / 3) * 64, (t % 3) * 64, As, Bs, tid);
    } else {
        const int b = blockIdx.x - 399;
        for (int i = tid; i < NN; i += 256) { c0s[i] = 0; c1s[i] = 0; }
        __syncthreads();
        const float* adjb = adj + (size_t)b * NN * NN;
        float2* pbg = pairs + (size_t)b * NN * NPAIR;
        for (int q = tid; q < NN * NN; q += 256) {
            int i = q / NN, j = q - i * NN;
            float a = adjb[q];
            if (a > 1e-5f) {
                int s = atomicAdd(&c0s[i], 1);
                pbg[i * NPAIR + s] = make_float2(a, __int_as_float(j));
            } else if (a > 0.f) {
                int s = atomicAdd(&c1s[i], 1);
                pbg[i * NPAIR + (NPAIR - 1) - s] = make_float2(a, __int_as_float(j));
            }
        }
        __syncthreads();
        for (int i = tid; i < NN; i += 256)
            cnts[b * NN + i] = make_int2(c0s[i], c1s[i]);
    }
}

// -------- spmm: one wave per row, GRP*64 cols; 2*GRP gathers in flight ------
template<int GRP>
__global__ __launch_bounds__(256)
void spmm_k(const float* __restrict__ t, int ld, int N,
            const float* __restrict__ bias,
            const float2* __restrict__ pairs, const int2* __restrict__ cnts,
            float* __restrict__ y)
{
    const int wave = threadIdx.x >> 6, lane = threadIdx.x & 63;
    const int r = blockIdx.x * 4 + wave;        // 0..8511
    const int b = r / NN;
    int  c[GRP], sc[GRP];
#pragma unroll
    for (int u = 0; u < GRP; ++u) {
        c[u] = u * 64 + lane;
        sc[u] = min(c[u], N - 1);               // clamp for safe loads
    }
    const float2* pb = pairs + (size_t)r * NPAIR;
    const float4* pq = reinterpret_cast<const float4*>(pb);
    const int2 cc = cnts[r];
    const float* tb = t + (size_t)b * NN * ld;

    float a0[GRP], a1[GRP];
#pragma unroll
    for (int u = 0; u < GRP; ++u) { a0[u] = 0.f; a1[u] = 0.f; }
    int q = 0;
    for (; q + 2 <= cc.x; q += 2) {             // 2 pairs -> 2*GRP loads in flight
        float4 p2 = pq[q >> 1];
        const float* r0 = tb + (size_t)__float_as_int(p2.y) * ld;
        const float* r1 = tb + (size_t)__float_as_int(p2.w) * ld;
#pragma unroll
        for (int u = 0; u < GRP; ++u) {
            a0[u] = fmaf(p2.x, r0[sc[u]], a0[u]);
            a1[u] = fmaf(p2.z, r1[sc[u]], a1[u]);
        }
    }
    if (q < cc.x) {
        float2 f = pb[q];
        const float* r0 = tb + (size_t)__float_as_int(f.y) * ld;
#pragma unroll
        for (int u = 0; u < GRP; ++u) a0[u] = fmaf(f.x, r0[sc[u]], a0[u]);
    }
    for (int v = 0; v < cc.y; ++v) {            // tiny-weight tail (spmm only)
        float2 f = pb[(NPAIR - 1) - v];
        const float* r0 = tb + (size_t)__float_as_int(f.y) * ld;
#pragma unroll
        for (int u = 0; u < GRP; ++u) a0[u] = fmaf(f.x, r0[sc[u]], a0[u]);
    }
#pragma unroll
    for (int u = 0; u < GRP; ++u)
        if (c[u] < N)
            y[(size_t)r * ld + c[u]] = fmaxf(a0[u] + a1[u] + bias[c[u]], 0.f);
}

// -------- pool: p[r,col] = max over front nbrs j of y[j,col] (y>=0) ---------
template<int GRP>
__global__ __launch_bounds__(256)
void pool_k(const float* __restrict__ y, int ld, int N,
            const float2* __restrict__ pairs, const int2* __restrict__ cnts,
            float* __restrict__ p)
{
    const int wave = threadIdx.x >> 6, lane = threadIdx.x & 63;
    const int r = blockIdx.x * 4 + wave;
    const int b = r / NN;
    int  c[GRP], sc[GRP];
#pragma unroll
    for (int u = 0; u < GRP; ++u) {
        c[u] = u * 64 + lane;
        sc[u] = min(c[u], N - 1);
    }
    const float2* pb = pairs + (size_t)r * NPAIR;
    const float4* pq = reinterpret_cast<const float4*>(pb);
    const int cx = cnts[r].x;
    const float* yb = y + (size_t)b * NN * ld;

    float m0[GRP], m1[GRP];
#pragma unroll
    for (int u = 0; u < GRP; ++u) { m0[u] = 0.f; m1[u] = 0.f; }
    int q = 0;
    for (; q + 2 <= cx; q += 2) {
        float4 p2 = pq[q >> 1];
        const float* r0 = yb + (size_t)__float_as_int(p2.y) * ld;
        const float* r1 = yb + (size_t)__float_as_int(p2.w) * ld;
#pragma unroll
        for (int u = 0; u < GRP; ++u) {
            m0[u] = fmaxf(m0[u], r0[sc[u]]);
            m1[u] = fmaxf(m1[u], r1[sc[u]]);
        }
    }
    if (q < cx) {
        const float* r0 = yb + (size_t)__float_as_int(pb[q].y) * ld;
#pragma unroll
        for (int u = 0; u < GRP; ++u) m0[u] = fmaxf(m0[u], r0[sc[u]]);
    }
#pragma unroll
    for (int u = 0; u < GRP; ++u)
        if (c[u] < N)
            p[(size_t)r * ld + c[u]] = fmaxf(m0[u], m1[u]);
}

// -------- t4: t4[r] = dot(pool3(y3)[r,0:75], gc4_w), one wave per row -------
__global__ __launch_bounds__(256)
void t4_k(const float* __restrict__ y3,   // ld 76, 75 valid cols
          const float2* __restrict__ pairs, const int2* __restrict__ cnts,
          const float* __restrict__ gc4_w,
          float* __restrict__ t4)         // 8512
{
    const int wave = threadIdx.x >> 6, lane = threadIdx.x & 63;
    const int r = blockIdx.x * 4 + wave;        // 0..8511
    const int b = r / NN;
    const float* yb = y3 + (size_t)b * NN * 76;
    const float2* pb = pairs + (size_t)r * NPAIR;
    const float4* pq = reinterpret_cast<const float4*>(pb);
    const int cx = cnts[r].x;
    const float gw0 = gc4_w[lane];                       // lane<=63<75 valid
    const float gw1 = (lane < 11) ? gc4_w[64 + lane] : 0.f;
    const int c2 = 64 + min(lane, 10);                   // safe 2nd col

    float m0 = 0.f, m1 = 0.f, n0 = 0.f, n1 = 0.f;
    int q = 0;
    for (; q + 2 <= cx; q += 2) {               // 4 gathers in flight
        float4 p2 = pq[q >> 1];
        const float* r0 = yb + (size_t)__float_as_int(p2.y) * 76;
        const float* r1 = yb + (size_t)__float_as_int(p2.w) * 76;
        m0 = fmaxf(m0, r0[lane]); m1 = fmaxf(m1, r0[c2]);
        n0 = fmaxf(n0, r1[lane]); n1 = fmaxf(n1, r1[c2]);
    }
    if (q < cx) {
        const float* r0 = yb + (size_t)__float_as_int(pb[q].y) * 76;
        m0 = fmaxf(m0, r0[lane]); m1 = fmaxf(m1, r0[c2]);
    }
    m0 = fmaxf(m0, n0); m1 = fmaxf(m1, n1);
    float v = m0 * gw0 + m1 * gw1;
#pragma unroll
    for (int off = 32; off; off >>= 1) v += __shfl_xor(v, off, 64);
    if (lane == 0) t4[r] = v;
}

// -------- tail: y4 = relu(A@t4+b4); fc1; fin; sigmoid (64 blocks, tiny) -----
__global__ __launch_bounds__(256)
void tail_k(const float* __restrict__ t4g,  // 8512
            const float2* __restrict__ pairs, const int2* __restrict__ cnts,
            const float* __restrict__ gc4_b,
            const float* __restrict__ fc1_w, const float* __restrict__ fc1_b,
            const float* __restrict__ fin_w, const float* __restrict__ fin_b,
            float* __restrict__ out)
{
    const int b = blockIdx.x, tid = threadIdx.x;
    __shared__ float t4S[NN], y4S[NN], rS[3];
    if (tid < NN) t4S[tid] = t4g[b * NN + tid];
    __syncthreads();
    if (tid < NN) {
        const float2* pb = pairs + ((size_t)b * NN + tid) * NPAIR;
        int2 c = cnts[b * NN + tid];
        float s = gc4_b[0];
        for (int q = 0; q < c.x; ++q) {
            float2 f = pb[q];
            s = fmaf(f.x, t4S[__float_as_int(f.y)], s);
        }
        for (int q = 0; q < c.y; ++q) {
            float2 f = pb[(NPAIR - 1) - q];
            s = fmaf(f.x, t4S[__float_as_int(f.y)], s);
        }
        y4S[tid] = fmaxf(s, 0.f);
    }
    __syncthreads();
    if (tid < 3) {
        float s = fc1_b[tid];
        for (int j = 0; j < 132; ++j)
            s = fmaf(y4S[1 + j], fc1_w[j * 3 + tid], s);
        rS[tid] = s;
    }
    __syncthreads();
    if (tid == 0) {
        float z = fin_b[0] + y4S[0] * fin_w[0] + rS[0] * fin_w[1]
                + rS[1] * fin_w[2] + rS[2] * fin_w[3];
        out[b] = 1.f / (1.f + expf(-z));
    }
}

extern "C" void kernel_launch(void* const* d_in, const int* in_sizes, int n_in,
                              void* d_out, int out_size, void* d_ws, size_t ws_size,
                              hipStream_t stream)
{
    const float* x     = (const float*)d_in[0];
    const float* adj   = (const float*)d_in[1];
    const float* emb_w = (const float*)d_in[2];
    const float* emb_b = (const float*)d_in[3];
    const float* gc1_w = (const float*)d_in[4];
    const float* gc1_b = (const float*)d_in[5];
    const float* gc2_w = (const float*)d_in[6];
    const float* gc2_b = (const float*)d_in[7];
    const float* gc3_w = (const float*)d_in[8];
    const float* gc3_b = (const float*)d_in[9];
    const float* gc4_w = (const float*)d_in[10];
    const float* gc4_b = (const float*)d_in[11];
    const float* fc1_w = (const float*)d_in[12];
    const float* fc1_b = (const float*)d_in[13];
    const float* fin_w = (const float*)d_in[14];
    const float* fin_b = (const float*)d_in[15];
    float* out = (float*)d_out;

    // ws: pairs 4.36MB | cnts 68KB | bA 8.72MB | bB 8.72MB | bC 8.72MB | t4
    const long MR = 64L * NN;                    // 8512
    float2* pairs = (float2*)d_ws;
    int2*   cnts  = (int2*)(pairs + MR * NPAIR);
    float*  bA    = (float*)(cnts + MR);
    float*  bB    = bA + MR * 256;
    float*  bC    = bB + MR * 256;
    float*  t4    = bC + MR * 256;               // 8512 floats

    // K1: emb GEMM (399 tiles) -> bC (h0, ld 152) + sparse prep (64 graphs)
    prep_emb_k<<<463, 256, 0, stream>>>(x, emb_w, emb_b, adj, pairs, cnts, bC);
    // K2: t1 = h0 @ gc1_w -> bA ld 256
    gemm_k<1, 1><<<532, 256, 0, stream>>>(bC, 152, 150, gc1_w, 256,
                                          bA, 256, 256, 4);
    // K3: y1 -> bB (one wave per row, 256 cols)
    spmm_k<4><<<2128, 256, 0, stream>>>(bA, 256, 256, gc1_b, pairs, cnts, bB);
    // K4: p1 -> bC
    pool_k<4><<<2128, 256, 0, stream>>>(bB, 256, 256, pairs, cnts, bC);
    // K5: t2 = p1 @ gc2_w -> bA ld 128
    gemm_k<1, 1><<<266, 256, 0, stream>>>(bC, 256, 256, gc2_w, 128,
                                          bA, 128, 128, 2);
    // K6: y2 -> bB
    spmm_k<2><<<2128, 256, 0, stream>>>(bA, 128, 128, gc2_b, pairs, cnts, bB);
    // K7: p2 -> bC
    pool_k<2><<<2128, 256, 0, stream>>>(bB, 128, 128, pairs, cnts, bC);
    // K8: t3 = p2 @ gc3_w -> bA ld 76 (padN=76 zero-fills col 75)
    gemm_k<1, 0><<<266, 256, 0, stream>>>(bC, 128, 128, gc3_w, 75,
                                          bA, 76, 76, 2);
    // K9: y3 -> bB (N=75, second col group masked)
    spmm_k<2><<<2128, 256, 0, stream>>>(bA, 76, 75, gc3_b, pairs, cnts, bB);
    // K10: t4[r] = pool3(y3)[r] . gc4_w  (one wave per row)
    t4_k<<<2128, 256, 0, stream>>>(bB, pairs, cnts, gc4_w, t4);
    // K11: tail
    tail_k<<<64, 256, 0, stream>>>(t4, pairs, cnts, gc4_b,
                                   fc1_w, fc1_b, fin_w, fin_b, out);
}